// Round 4
// baseline (613.472 us; speedup 1.0000x reference)
//
#include <hip/hip_runtime.h>
#include <math.h>

// ---------------------------------------------------------------------------
// JointsGait fused v2: barrier-light MFMA streams.
// layer = ReLU(((A_hat @ H) @ W + b) * att), A_hat constant 17x17.
// Block = 4 graphs. H stored row-major [80][256] f16 in LDS with XOR-chunk
// swizzle (serves column-wise mix AND b128 MFMA frag reads conflict-free).
// Per layer: in-place mix over full K (1 barrier) -> straight-line MFMA loop
// (0 barriers) -> epilogue (2 barriers). Waves split 1x4 over N (disjoint B).
// Head: stage pooled 16x1536 once, 288 MFMA straight-line, fused BN+L2norm.
// ---------------------------------------------------------------------------

typedef _Float16 f16;
typedef _Float16 v8h __attribute__((ext_vector_type(8)));
typedef float    v4f __attribute__((ext_vector_type(4)));

namespace {

constexpr int BA[19] = {15,13,16,14,11, 5, 6, 5, 5, 6, 7, 8, 1, 0, 0, 1, 2, 3, 4};
constexpr int BB[19] = {13,11,14,12,12,11,12, 6, 7, 8, 9,10, 2, 1, 2, 3, 4, 5, 6};
constexpr float DINV[17] = {
  0.57735026919f, 0.5f, 0.5f, 0.57735026919f, 0.57735026919f,
  0.44721359550f, 0.44721359550f, 0.57735026919f, 0.57735026919f,
  0.70710678119f, 0.70710678119f, 0.5f, 0.5f,
  0.57735026919f, 0.57735026919f, 0.70710678119f, 0.70710678119f};

__device__ __forceinline__ void mix17(const float* h, float* g){
  #pragma unroll
  for (int i=0;i<17;i++) g[i] = (DINV[i]*DINV[i])*h[i];
  #pragma unroll
  for (int e=0;e<19;e++){
    const float c = DINV[BA[e]]*DINV[BB[e]];
    g[BA[e]] += c*h[BB[e]];
    g[BB[e]] += c*h[BA[e]];
  }
}

// H element index with XOR-chunk swizzle (row stride 256 f16 = 512B).
// Chunk (8 f16) index bits 0..2 XORed with row&7 -> b128 frag reads hit the
// 128B/clk LDS floor; column accesses spread over all banks (2-way, free).
__device__ __forceinline__ int hswz(int row, int k){
  return row*256 + (k & ~63) + (((((k>>3)&7) ^ (row&7)))<<3) + (k&7);
}

// ---- mix phase: G = A_hat @ H in place, column-private per thread ----------
template<int KP, bool FIRST>
__device__ __forceinline__ void mix_phase(f16* __restrict__ H,
    const float* __restrict__ x, int g0, int G, int t)
{
  const int g = t>>6, k0 = t&63;
  #pragma unroll
  for (int it=0; it<KP/64; ++it){
    const int k = k0 + it*64;
    float h[17], gv[17];
    if constexpr (FIRST){
      const bool live = (k < 2) && (g0+g < G);
      #pragma unroll
      for (int j=0;j<17;++j) h[j] = live ? x[(size_t)(g0+g)*34 + j*2 + k] : 0.f;
    } else {
      #pragma unroll
      for (int j=0;j<17;++j) h[j] = (float)H[hswz(g*20+j, k)];
    }
    mix17(h, gv);
    #pragma unroll
    for (int j=0;j<17;++j) H[hswz(g*20+j, k)] = (f16)gv[j];
    if constexpr (FIRST){
      #pragma unroll
      for (int j=17;j<20;++j) H[hswz(g*20+j, k)] = (f16)0.f;   // pad rows -> 0
    }
  }
  __syncthreads();
}

// ---- MFMA phase: H' = relu((G @ W + b)*att), straight-line over K ----------
template<int KP, int DOUT>
__device__ __forceinline__ void mfma_phase(f16* __restrict__ H,
    const f16* __restrict__ Wt, const float* __restrict__ bias,
    const float* __restrict__ attp, int g0, int t)
{
  constexpr int NTW = DOUT/64;          // 16-wide n-tiles per wave (1x4 N split)
  const int w = t>>6, lane = t&63, m = lane&15, q = lane>>4;
  const int cb = w*(DOUT/4);

  v4f acc[5][NTW];
  #pragma unroll
  for (int a=0;a<5;++a)
    #pragma unroll
    for (int b=0;b<NTW;++b) acc[a][b] = v4f{0.f,0.f,0.f,0.f};

  #pragma unroll
  for (int ks=0; ks<KP/32; ++ks){
    v8h af[5];
    #pragma unroll
    for (int mt=0;mt<5;++mt)
      af[mt] = *(const v8h*)(H + hswz(mt*16+m, ks*32 + q*8));
    #pragma unroll
    for (int nt=0;nt<NTW;++nt){
      const v8h bf = *(const v8h*)(Wt + (size_t)(cb+nt*16+m)*KP + ks*32 + q*8);
      #pragma unroll
      for (int mt=0;mt<5;++mt)
        acc[mt][nt] = __builtin_amdgcn_mfma_f32_16x16x32_f16(af[mt], bf, acc[mt][nt], 0,0,0);
    }
  }
  __syncthreads();                       // all frag reads done before overwrite

  #pragma unroll
  for (int mt=0;mt<5;++mt){
    const int r0 = mt*16 + q*4;
    const int g = r0/20, j0 = r0 - g*20; // quads never cross 20-row slots
    const v4f a4 = *(const v4f*)(attp + (size_t)(g0+g)*20 + j0);
    #pragma unroll
    for (int nt=0;nt<NTW;++nt){
      const int c = cb + nt*16 + m;
      const float bc = bias[c];
      #pragma unroll
      for (int i=0;i<4;++i)
        H[hswz(r0+i, c)] = (f16)fmaxf((acc[mt][nt][i]+bc)*a4[i], 0.f);
    }
  }
  __syncthreads();
}

} // namespace

// ---------------- prep: f16 W^T (k-padded), f16 fcW, BN fold, padded att -----
__global__ void prep_kernel(
    const float* __restrict__ W1, const float* __restrict__ W2,
    const float* __restrict__ W3, const float* __restrict__ W4,
    const float* __restrict__ W5, const float* __restrict__ W6,
    const float* __restrict__ W7, const float* __restrict__ W8,
    const float* __restrict__ W9,
    const float* __restrict__ fcW, const float* __restrict__ bng,
    const float* __restrict__ bnb, const float* __restrict__ bnrm,
    const float* __restrict__ bnrv, const float* __restrict__ att,
    f16* __restrict__ wt, f16* __restrict__ fcWh,
    float* __restrict__ bnsc, float* __restrict__ bnsh,
    float* __restrict__ attp, int G)
{
  const int idx = blockIdx.x*blockDim.x + threadIdx.x;
  const int stride = gridDim.x*blockDim.x;
  const float* Ws[9] = {W1,W2,W3,W4,W5,W6,W7,W8,W9};
  const int DINs[9]  = {2,64,64,64,128,128,128,256,256};
  const int DOUTs[9] = {64,64,64,128,128,128,256,256,256};
  const int KPs[9]   = {64,64,64,64,128,128,128,256,256};
  const int OFFs[9]  = {0,4096,8192,12288,20480,36864,53248,86016,151552};
  for (int l=0;l<9;++l){
    const float* W = Ws[l];
    const int DIN=DINs[l], DOUT=DOUTs[l], KP=KPs[l];
    f16* dst = wt + OFFs[l];
    const int n = DOUT*KP;
    for (int i=idx;i<n;i+=stride){
      const int row = i/KP, k = i - row*KP;           // row = out index
      dst[i] = (k<DIN) ? (f16)W[k*DOUT+row] : (f16)0.f;
    }
  }
  for (int i=idx;i<6*256*256;i+=stride) fcWh[i] = (f16)fcW[i];
  for (int i=idx;i<1536;i+=stride){
    const float sc = bng[i] * rsqrtf(bnrv[i] + 1e-5f);
    bnsc[i] = sc; bnsh[i] = bnb[i] - bnrm[i]*sc;
  }
  for (int i=idx;i<G*20;i+=stride){
    const int g = i/20, j = i - g*20;
    attp[i] = (j<17) ? att[(size_t)g*17 + j] : 0.f;
  }
}

// ---------------- fused GCN (9 layers) + pooling -----------------------------
__global__ __launch_bounds__(256, 3)
void gcn_kernel(const float* __restrict__ x, const f16* __restrict__ wt,
                const float* __restrict__ attp,
                const float* __restrict__ b1, const float* __restrict__ b2,
                const float* __restrict__ b3, const float* __restrict__ b4,
                const float* __restrict__ b5, const float* __restrict__ b6,
                const float* __restrict__ b7, const float* __restrict__ b8,
                const float* __restrict__ b9,
                f16* __restrict__ pooled, int G)
{
  __shared__ __align__(16) f16 H[80*256];   // 40960 B, the only LDS
  const int t = threadIdx.x;
  const int g0 = blockIdx.x*4;

  mix_phase< 64,true >(H, x, g0, G, t);  mfma_phase< 64, 64>(H, wt+0,      b1, attp, g0, t);
  mix_phase< 64,false>(H, x, g0, G, t);  mfma_phase< 64, 64>(H, wt+4096,   b2, attp, g0, t);
  mix_phase< 64,false>(H, x, g0, G, t);  mfma_phase< 64, 64>(H, wt+8192,   b3, attp, g0, t);
  mix_phase< 64,false>(H, x, g0, G, t);  mfma_phase< 64,128>(H, wt+12288,  b4, attp, g0, t);
  mix_phase<128,false>(H, x, g0, G, t);  mfma_phase<128,128>(H, wt+20480,  b5, attp, g0, t);
  mix_phase<128,false>(H, x, g0, G, t);  mfma_phase<128,128>(H, wt+36864,  b6, attp, g0, t);
  mix_phase<128,false>(H, x, g0, G, t);  mfma_phase<128,256>(H, wt+53248,  b7, attp, g0, t);
  mix_phase<256,false>(H, x, g0, G, t);  mfma_phase<256,256>(H, wt+86016,  b8, attp, g0, t);
  mix_phase<256,false>(H, x, g0, G, t);  mfma_phase<256,256>(H, wt+151552, b9, attp, g0, t);

  // ---- JRPP pooling (trailing barrier of layer 9 already passed) ----
  const int g = t>>6, gg = g0 + g;
  if (gg < G){
    f16* op = pooled + (size_t)gg*1536;
    #pragma unroll
    for (int it=0; it<4; ++it){
      const int k = (t&63) + it*64;
      float h[17];
      #pragma unroll
      for (int j=0;j<17;++j) h[j] = (float)H[hswz(g*20+j, k)];
      const float head = h[0]+h[1]+h[2]+h[3]+h[4];
      const float sa   = head + h[5]+h[6]+h[7]+h[8]+h[9]+h[10];
      const float sb   = h[11]+h[12]+h[13]+h[14]+h[15]+h[16];
      op[0*256+k] = (f16)((sa+sb)*(1.0f/17.0f));
      op[1*256+k] = (f16)(sa*(1.0f/11.0f));
      op[2*256+k] = (f16)(sb*(1.0f/6.0f));
      op[3*256+k] = (f16)(head*(1.0f/5.0f));
      op[4*256+k] = (f16)((h[5]+h[7]+h[9]+h[12]+h[14]+h[16])*(1.0f/6.0f));
      op[5*256+k] = (f16)((h[6]+h[8]+h[10]+h[11]+h[13]+h[15])*(1.0f/6.0f));
    }
  }
}

// ---------------- head: stage once, 288 MFMA straight-line, BN + L2-norm -----
__global__ __launch_bounds__(256, 3)
void head_kernel(const f16* __restrict__ pooled, const f16* __restrict__ fcWh,
                 const float* __restrict__ fcB, const float* __restrict__ bnsc,
                 const float* __restrict__ bnsh, float* __restrict__ out, int G)
{
  __shared__ __align__(16) f16 Ap[16*1536];   // 49152 B, swizzled
  __shared__ float red[64];
  __shared__ float invn[16];
  const int t = threadIdx.x, w = t>>6, lane = t&63;
  const int m = lane&15, q = lane>>4;
  const int g0 = blockIdx.x*16;
  const int cb = w*64;

  // stage pooled rows (all 6 scales) once
  for (int id=t; id<16*192; id+=256){
    const int row = id/192, cc = id - row*192;
    v8h v = v8h{0,0,0,0,0,0,0,0};
    const int gg = g0 + row;
    if (gg < G) v = *(const v8h*)(pooled + (size_t)gg*1536 + cc*8);
    const int pc = (cc & ~7) | ((cc&7) ^ (row&7));
    *(v8h*)(Ap + row*1536 + pc*8) = v;
  }
  __syncthreads();

  v4f acc[6][4];
  #pragma unroll
  for (int s=0;s<6;++s)
    #pragma unroll
    for (int nt=0;nt<4;++nt) acc[s][nt] = v4f{0.f,0.f,0.f,0.f};

  #pragma unroll
  for (int s=0;s<6;++s){
    #pragma unroll
    for (int ks=0; ks<8; ++ks){
      const int c = s*32 + ks*4 + q;
      const v8h af = *(const v8h*)(Ap + m*1536 + ((c & ~7) | ((c&7) ^ (m&7)))*8);
      #pragma unroll
      for (int nt=0;nt<4;++nt){
        const v8h bf = *(const v8h*)(fcWh + (size_t)(s*256 + cb + nt*16 + m)*256 + ks*32 + q*8);
        acc[s][nt] = __builtin_amdgcn_mfma_f32_16x16x32_f16(af, bf, acc[s][nt], 0,0,0);
      }
    }
  }

  // BN in place + per-graph sum of squares
  float ss[4] = {0.f,0.f,0.f,0.f};
  #pragma unroll
  for (int s=0;s<6;++s)
    #pragma unroll
    for (int nt=0;nt<4;++nt){
      const int idx = s*256 + cb + nt*16 + m;
      const float bc = fcB[idx], sc = bnsc[idx], sh = bnsh[idx];
      #pragma unroll
      for (int i=0;i<4;++i){
        const float f = (acc[s][nt][i] + bc)*sc + sh;
        acc[s][nt][i] = f;
        ss[i] += f*f;
      }
    }

  #pragma unroll
  for (int off=1; off<16; off<<=1)
    #pragma unroll
    for (int i=0;i<4;++i) ss[i] += __shfl_xor(ss[i], off, 64);
  if (m==0)
    #pragma unroll
    for (int i=0;i<4;++i) red[w*16 + q*4 + i] = ss[i];
  __syncthreads();
  if (t < 16){
    const float s4 = red[t] + red[16+t] + red[32+t] + red[48+t];
    invn[t] = 1.f / fmaxf(sqrtf(s4), 1e-12f);
  }
  __syncthreads();
  float iv[4];
  #pragma unroll
  for (int i=0;i<4;++i) iv[i] = invn[q*4+i];
  #pragma unroll
  for (int s=0;s<6;++s)
    #pragma unroll
    for (int nt=0;nt<4;++nt)
      #pragma unroll
      for (int i=0;i<4;++i){
        const int gg = g0 + q*4 + i;
        if (gg < G)
          out[(size_t)gg*1536 + s*256 + cb + nt*16 + m] = acc[s][nt][i]*iv[i];
      }
}

extern "C" void kernel_launch(void* const* d_in, const int* in_sizes, int n_in,
                              void* d_out, int out_size, void* d_ws, size_t ws_size,
                              hipStream_t stream) {
  (void)n_in; (void)out_size; (void)ws_size;
  const float* x   = (const float*)d_in[0];
  const float* att = (const float*)d_in[1];
  const float* W[9]; const float* B[9];
  for (int i=0;i<9;i++){ W[i]=(const float*)d_in[3+2*i]; B[i]=(const float*)d_in[4+2*i]; }
  const float* fcW  = (const float*)d_in[21];
  const float* fcB  = (const float*)d_in[22];
  const float* bn_g = (const float*)d_in[23];
  const float* bn_b = (const float*)d_in[24];
  const float* bn_rm= (const float*)d_in[25];
  const float* bn_rv= (const float*)d_in[26];
  float* out = (float*)d_out;

  const int G = in_sizes[1] / 17;

  // ws layout
  char* ws = (char*)d_ws;
  f16*   wt   = (f16*)(ws);                       // 434176 B
  f16*   fcWh = (f16*)(ws + 434176);              // 786432 B
  float* bnsc = (float*)(ws + 1220608);           // 6144 B
  float* bnsh = (float*)(ws + 1226752);           // 6144 B
  float* attp = (float*)(ws + 1232896);           // G*20*4 B
  size_t poolOff = (1232896 + (size_t)G*80 + 255) & ~(size_t)255;
  f16* pooled = (f16*)(ws + poolOff);             // G*1536*2 B

  prep_kernel<<<256, 256, 0, stream>>>(
      W[0],W[1],W[2],W[3],W[4],W[5],W[6],W[7],W[8],
      fcW, bn_g, bn_b, bn_rm, bn_rv, att,
      wt, fcWh, bnsc, bnsh, attp, G);

  const int gb = (G + 3) / 4;
  gcn_kernel<<<gb, 256, 0, stream>>>(
      x, wt, attp,
      B[0],B[1],B[2],B[3],B[4],B[5],B[6],B[7],B[8],
      pooled, G);

  head_kernel<<<(G + 15)/16, 256, 0, stream>>>(
      pooled, fcWh, fcB, bnsc, bnsh, out, G);
}

// Round 5
// 460.941 us; speedup vs baseline: 1.3309x; 1.3309x over previous
//
#include <hip/hip_runtime.h>
#include <math.h>

// ---------------------------------------------------------------------------
// JointsGait fused v3.
// layer = ReLU(((A_hat @ H) @ W + b) * att), A_hat constant 17x17.
// Block = 4 graphs. H row-major [80][256] f16 in LDS, XOR-chunk swizzle.
// Per layer: vectorized in-place mix (v4h/v2h row segments, all 256 threads,
// 1 barrier) -> straight-line MFMA (0 barriers) -> epilogue (2 barriers).
// launch_bounds(256,2): no spills (R4 lesson: bounds-3 split the unified
// VGPR/AGPR file 84/80 and spilled every VALU phase -> 700MB scratch traffic).
// ---------------------------------------------------------------------------

typedef _Float16 f16;
typedef _Float16 v2h __attribute__((ext_vector_type(2)));
typedef _Float16 v4h __attribute__((ext_vector_type(4)));
typedef _Float16 v8h __attribute__((ext_vector_type(8)));
typedef float    v4f __attribute__((ext_vector_type(4)));

namespace {

constexpr int BA[19] = {15,13,16,14,11, 5, 6, 5, 5, 6, 7, 8, 1, 0, 0, 1, 2, 3, 4};
constexpr int BB[19] = {13,11,14,12,12,11,12, 6, 7, 8, 9,10, 2, 1, 2, 3, 4, 5, 6};
constexpr float DINV[17] = {
  0.57735026919f, 0.5f, 0.5f, 0.57735026919f, 0.57735026919f,
  0.44721359550f, 0.44721359550f, 0.57735026919f, 0.57735026919f,
  0.70710678119f, 0.70710678119f, 0.5f, 0.5f,
  0.57735026919f, 0.57735026919f, 0.70710678119f, 0.70710678119f};

__device__ __forceinline__ void mix17(const float* h, float* g){
  #pragma unroll
  for (int i=0;i<17;i++) g[i] = (DINV[i]*DINV[i])*h[i];
  #pragma unroll
  for (int e=0;e<19;e++){
    const float c = DINV[BA[e]]*DINV[BB[e]];
    g[BA[e]] += c*h[BB[e]];
    g[BB[e]] += c*h[BA[e]];
  }
}

// H element index with XOR-chunk swizzle (row stride 256 f16 = 512B).
__device__ __forceinline__ int hswz(int row, int k){
  return row*256 + (k & ~63) + (((((k>>3)&7) ^ (row&7)))<<3) + (k&7);
}

template<int VW>
__device__ __forceinline__ void ldh(const f16* p, float* d){
  if constexpr (VW==4){ const v4h v = *(const v4h*)p; d[0]=v[0];d[1]=v[1];d[2]=v[2];d[3]=v[3]; }
  else if constexpr (VW==2){ const v2h v = *(const v2h*)p; d[0]=v[0];d[1]=v[1]; }
  else { d[0] = (float)p[0]; }
}
template<int VW>
__device__ __forceinline__ void sth(f16* p, const float* d){
  if constexpr (VW==4){ v4h v; v[0]=(f16)d[0];v[1]=(f16)d[1];v[2]=(f16)d[2];v[3]=(f16)d[3]; *(v4h*)p = v; }
  else if constexpr (VW==2){ v2h v; v[0]=(f16)d[0];v[1]=(f16)d[1]; *(v2h*)p = v; }
  else { p[0] = (f16)d[0]; }
}

// ---- layer-1 init: H = A_hat @ x (cols 0..1), zeros elsewhere --------------
__device__ __forceinline__ void first_phase(f16* __restrict__ H,
    const float* __restrict__ x, int g0, int G, int t)
{
  const int g = t>>6, k = t&63;
  float h[17], gv[17];
  const bool live = (k < 2) && (g0+g < G);
  #pragma unroll
  for (int i=0;i<17;++i) h[i] = live ? x[(size_t)(g0+g)*34 + i*2 + k] : 0.f;
  mix17(h, gv);
  #pragma unroll
  for (int i=0;i<17;++i) H[hswz(g*20+i, k)] = (f16)gv[i];
  #pragma unroll
  for (int j=17;j<20;++j) H[hswz(g*20+j, k)] = (f16)0.f;
  __syncthreads();
}

// ---- mix phase: G = A_hat @ H in place, VW-wide column groups --------------
// VW = KP/64 -> 64 groups/graph -> all 256 threads active for every KP.
template<int KP>
__device__ __forceinline__ void mix_phase(f16* __restrict__ H, int t){
  constexpr int VW = KP/64;
  const int g = t>>6, k0 = (t&63)*VW;
  float gv[17*VW];
  #pragma unroll
  for (int i=0;i<17*VW;++i) gv[i] = 0.f;
  #pragma unroll
  for (int i=0;i<17;++i){
    float hi[VW];
    ldh<VW>(H + hswz(g*20+i, k0), hi);
    const float dii = DINV[i]*DINV[i];
    #pragma unroll
    for (int v=0;v<VW;++v) gv[i*VW+v] += dii*hi[v];
    #pragma unroll
    for (int e=0;e<19;++e){
      if (BA[e]==i){
        const float c = DINV[BA[e]]*DINV[BB[e]];
        #pragma unroll
        for (int v=0;v<VW;++v) gv[BB[e]*VW+v] += c*hi[v];
      }
      if (BB[e]==i){
        const float c = DINV[BA[e]]*DINV[BB[e]];
        #pragma unroll
        for (int v=0;v<VW;++v) gv[BA[e]*VW+v] += c*hi[v];
      }
    }
  }
  #pragma unroll
  for (int i=0;i<17;++i) sth<VW>(H + hswz(g*20+i, k0), gv + i*VW);
  __syncthreads();
}

// ---- MFMA phase: H' = relu((G @ W + b)*att), straight-line over K ----------
template<int KP, int DOUT>
__device__ __forceinline__ void mfma_phase(f16* __restrict__ H,
    const f16* __restrict__ Wt, const float* __restrict__ bias,
    const float* __restrict__ attp, int g0, int t)
{
  constexpr int NTW = DOUT/64;          // 16-wide n-tiles per wave (1x4 N split)
  const int w = t>>6, lane = t&63, m = lane&15, q = lane>>4;
  const int cb = w*(DOUT/4);

  v4f acc[5][NTW];
  #pragma unroll
  for (int a=0;a<5;++a)
    #pragma unroll
    for (int b=0;b<NTW;++b) acc[a][b] = v4f{0.f,0.f,0.f,0.f};

  #pragma unroll
  for (int ks=0; ks<KP/32; ++ks){
    v8h af[5];
    #pragma unroll
    for (int mt=0;mt<5;++mt)
      af[mt] = *(const v8h*)(H + hswz(mt*16+m, ks*32 + q*8));
    #pragma unroll
    for (int nt=0;nt<NTW;++nt){
      const v8h bf = *(const v8h*)(Wt + (size_t)(cb+nt*16+m)*KP + ks*32 + q*8);
      #pragma unroll
      for (int mt=0;mt<5;++mt)
        acc[mt][nt] = __builtin_amdgcn_mfma_f32_16x16x32_f16(af[mt], bf, acc[mt][nt], 0,0,0);
    }
  }
  __syncthreads();                       // all frag reads done before overwrite

  #pragma unroll
  for (int mt=0;mt<5;++mt){
    const int r0 = mt*16 + q*4;
    const int g = r0/20, j0 = r0 - g*20; // quads never cross 20-row slots
    const v4f a4 = *(const v4f*)(attp + (size_t)(g0+g)*20 + j0);  // pad rows: att=0
    #pragma unroll
    for (int nt=0;nt<NTW;++nt){
      const int c = cb + nt*16 + m;
      const float bc = bias[c];
      #pragma unroll
      for (int i=0;i<4;++i)
        H[hswz(r0+i, c)] = (f16)fmaxf((acc[mt][nt][i]+bc)*a4[i], 0.f);
    }
  }
  __syncthreads();
}

} // namespace

// ---------------- prep: f16 W^T (k-padded), f16 fcW, BN fold, padded att -----
__global__ void prep_kernel(
    const float* __restrict__ W1, const float* __restrict__ W2,
    const float* __restrict__ W3, const float* __restrict__ W4,
    const float* __restrict__ W5, const float* __restrict__ W6,
    const float* __restrict__ W7, const float* __restrict__ W8,
    const float* __restrict__ W9,
    const float* __restrict__ fcW, const float* __restrict__ bng,
    const float* __restrict__ bnb, const float* __restrict__ bnrm,
    const float* __restrict__ bnrv, const float* __restrict__ att,
    f16* __restrict__ wt, f16* __restrict__ fcWh,
    float* __restrict__ bnsc, float* __restrict__ bnsh,
    float* __restrict__ attp, int G)
{
  const int idx = blockIdx.x*blockDim.x + threadIdx.x;
  const int stride = gridDim.x*blockDim.x;
  const float* Ws[9] = {W1,W2,W3,W4,W5,W6,W7,W8,W9};
  const int DINs[9]  = {2,64,64,64,128,128,128,256,256};
  const int DOUTs[9] = {64,64,64,128,128,128,256,256,256};
  const int KPs[9]   = {64,64,64,64,128,128,128,256,256};
  const int OFFs[9]  = {0,4096,8192,12288,20480,36864,53248,86016,151552};
  for (int l=0;l<9;++l){
    const float* W = Ws[l];
    const int DIN=DINs[l], DOUT=DOUTs[l], KP=KPs[l];
    f16* dst = wt + OFFs[l];
    const int n = DOUT*KP;
    for (int i=idx;i<n;i+=stride){
      const int row = i/KP, k = i - row*KP;           // row = out index
      dst[i] = (k<DIN) ? (f16)W[k*DOUT+row] : (f16)0.f;
    }
  }
  for (int i=idx;i<6*256*256;i+=stride) fcWh[i] = (f16)fcW[i];
  for (int i=idx;i<1536;i+=stride){
    const float sc = bng[i] * rsqrtf(bnrv[i] + 1e-5f);
    bnsc[i] = sc; bnsh[i] = bnb[i] - bnrm[i]*sc;
  }
  for (int i=idx;i<G*20;i+=stride){
    const int g = i/20, j = i - g*20;
    attp[i] = (j<17) ? att[(size_t)g*17 + j] : 0.f;
  }
}

// ---------------- fused GCN (9 layers) + pooling -----------------------------
__global__ __launch_bounds__(256, 2)
void gcn_kernel(const float* __restrict__ x, const f16* __restrict__ wt,
                const float* __restrict__ attp,
                const float* __restrict__ b1, const float* __restrict__ b2,
                const float* __restrict__ b3, const float* __restrict__ b4,
                const float* __restrict__ b5, const float* __restrict__ b6,
                const float* __restrict__ b7, const float* __restrict__ b8,
                const float* __restrict__ b9,
                f16* __restrict__ pooled, int G)
{
  __shared__ __align__(16) f16 H[80*256];   // 40960 B, the only LDS
  const int t = threadIdx.x;
  const int g0 = blockIdx.x*4;

  first_phase(H, x, g0, G, t);
  mfma_phase< 64, 64>(H, wt+0,      b1, attp, g0, t);
  mix_phase< 64>(H, t);  mfma_phase< 64, 64>(H, wt+4096,   b2, attp, g0, t);
  mix_phase< 64>(H, t);  mfma_phase< 64, 64>(H, wt+8192,   b3, attp, g0, t);
  mix_phase< 64>(H, t);  mfma_phase< 64,128>(H, wt+12288,  b4, attp, g0, t);
  mix_phase<128>(H, t);  mfma_phase<128,128>(H, wt+20480,  b5, attp, g0, t);
  mix_phase<128>(H, t);  mfma_phase<128,128>(H, wt+36864,  b6, attp, g0, t);
  mix_phase<128>(H, t);  mfma_phase<128,256>(H, wt+53248,  b7, attp, g0, t);
  mix_phase<256>(H, t);  mfma_phase<256,256>(H, wt+86016,  b8, attp, g0, t);
  mix_phase<256>(H, t);  mfma_phase<256,256>(H, wt+151552, b9, attp, g0, t);

  // ---- JRPP pooling: v4h column quads, running sums, b64 global stores ----
  const int g = t>>6, k0 = (t&63)*4, gg = g0 + g;
  if (gg < G){
    float sA[4]={0,0,0,0}, sB[4]={0,0,0,0}, sH[4]={0,0,0,0},
          sL[4]={0,0,0,0}, sR[4]={0,0,0,0};
    #pragma unroll
    for (int i=0;i<17;++i){
      float hi[4];
      ldh<4>(H + hswz(g*20+i, k0), hi);
      #pragma unroll
      for (int v=0;v<4;++v){
        if (i<11) sA[v]+=hi[v]; else sB[v]+=hi[v];
        if (i<5)  sH[v]+=hi[v];
        if (i==5||i==7||i==9||i==12||i==14||i==16)  sL[v]+=hi[v];
        if (i==6||i==8||i==10||i==11||i==13||i==15) sR[v]+=hi[v];
      }
    }
    f16* op = pooled + (size_t)gg*1536 + k0;
    v4h o;
    #pragma unroll
    for (int v=0;v<4;++v) o[v]=(f16)((sA[v]+sB[v])*(1.0f/17.0f)); *(v4h*)(op+0*256)=o;
    #pragma unroll
    for (int v=0;v<4;++v) o[v]=(f16)(sA[v]*(1.0f/11.0f));         *(v4h*)(op+1*256)=o;
    #pragma unroll
    for (int v=0;v<4;++v) o[v]=(f16)(sB[v]*(1.0f/6.0f));          *(v4h*)(op+2*256)=o;
    #pragma unroll
    for (int v=0;v<4;++v) o[v]=(f16)(sH[v]*(1.0f/5.0f));          *(v4h*)(op+3*256)=o;
    #pragma unroll
    for (int v=0;v<4;++v) o[v]=(f16)(sL[v]*(1.0f/6.0f));          *(v4h*)(op+4*256)=o;
    #pragma unroll
    for (int v=0;v<4;++v) o[v]=(f16)(sR[v]*(1.0f/6.0f));          *(v4h*)(op+5*256)=o;
  }
}

// ---------------- head: stage once, 288 MFMA straight-line, BN + L2-norm -----
__global__ __launch_bounds__(256, 2)
void head_kernel(const f16* __restrict__ pooled, const f16* __restrict__ fcWh,
                 const float* __restrict__ fcB, const float* __restrict__ bnsc,
                 const float* __restrict__ bnsh, float* __restrict__ out, int G)
{
  __shared__ __align__(16) f16 Ap[16*1536];   // 49152 B, swizzled
  __shared__ float red[64];
  __shared__ float invn[16];
  const int t = threadIdx.x, w = t>>6, lane = t&63;
  const int m = lane&15, q = lane>>4;
  const int g0 = blockIdx.x*16;
  const int cb = w*64;

  // stage pooled rows (all 6 scales) once
  for (int id=t; id<16*192; id+=256){
    const int row = id/192, cc = id - row*192;
    v8h v = v8h{0,0,0,0,0,0,0,0};
    const int gg = g0 + row;
    if (gg < G) v = *(const v8h*)(pooled + (size_t)gg*1536 + cc*8);
    const int pc = (cc & ~7) | ((cc&7) ^ (row&7));
    *(v8h*)(Ap + row*1536 + pc*8) = v;
  }
  __syncthreads();

  v4f acc[6][4];
  #pragma unroll
  for (int s=0;s<6;++s)
    #pragma unroll
    for (int nt=0;nt<4;++nt) acc[s][nt] = v4f{0.f,0.f,0.f,0.f};

  #pragma unroll
  for (int s=0;s<6;++s){
    #pragma unroll
    for (int ks=0; ks<8; ++ks){
      const int c = s*32 + ks*4 + q;
      const v8h af = *(const v8h*)(Ap + m*1536 + ((c & ~7) | ((c&7) ^ (m&7)))*8);
      #pragma unroll
      for (int nt=0;nt<4;++nt){
        const v8h bf = *(const v8h*)(fcWh + (size_t)(s*256 + cb + nt*16 + m)*256 + ks*32 + q*8);
        acc[s][nt] = __builtin_amdgcn_mfma_f32_16x16x32_f16(af, bf, acc[s][nt], 0,0,0);
      }
    }
  }

  // BN in place + per-graph sum of squares
  float ss[4] = {0.f,0.f,0.f,0.f};
  #pragma unroll
  for (int s=0;s<6;++s)
    #pragma unroll
    for (int nt=0;nt<4;++nt){
      const int idx = s*256 + cb + nt*16 + m;
      const float bc = fcB[idx], sc = bnsc[idx], sh = bnsh[idx];
      #pragma unroll
      for (int i=0;i<4;++i){
        const float f = (acc[s][nt][i] + bc)*sc + sh;
        acc[s][nt][i] = f;
        ss[i] += f*f;
      }
    }

  #pragma unroll
  for (int off=1; off<16; off<<=1)
    #pragma unroll
    for (int i=0;i<4;++i) ss[i] += __shfl_xor(ss[i], off, 64);
  if (m==0)
    #pragma unroll
    for (int i=0;i<4;++i) red[w*16 + q*4 + i] = ss[i];
  __syncthreads();
  if (t < 16){
    const float s4 = red[t] + red[16+t] + red[32+t] + red[48+t];
    invn[t] = 1.f / fmaxf(sqrtf(s4), 1e-12f);
  }
  __syncthreads();
  float iv[4];
  #pragma unroll
  for (int i=0;i<4;++i) iv[i] = invn[q*4+i];
  #pragma unroll
  for (int s=0;s<6;++s)
    #pragma unroll
    for (int nt=0;nt<4;++nt)
      #pragma unroll
      for (int i=0;i<4;++i){
        const int gg = g0 + q*4 + i;
        if (gg < G)
          out[(size_t)gg*1536 + s*256 + cb + nt*16 + m] = acc[s][nt][i]*iv[i];
      }
}

extern "C" void kernel_launch(void* const* d_in, const int* in_sizes, int n_in,
                              void* d_out, int out_size, void* d_ws, size_t ws_size,
                              hipStream_t stream) {
  (void)n_in; (void)out_size; (void)ws_size;
  const float* x   = (const float*)d_in[0];
  const float* att = (const float*)d_in[1];
  const float* W[9]; const float* B[9];
  for (int i=0;i<9;i++){ W[i]=(const float*)d_in[3+2*i]; B[i]=(const float*)d_in[4+2*i]; }
  const float* fcW  = (const float*)d_in[21];
  const float* fcB  = (const float*)d_in[22];
  const float* bn_g = (const float*)d_in[23];
  const float* bn_b = (const float*)d_in[24];
  const float* bn_rm= (const float*)d_in[25];
  const float* bn_rv= (const float*)d_in[26];
  float* out = (float*)d_out;

  const int G = in_sizes[1] / 17;

  // ws layout
  char* ws = (char*)d_ws;
  f16*   wt   = (f16*)(ws);                       // 434176 B
  f16*   fcWh = (f16*)(ws + 434176);              // 786432 B
  float* bnsc = (float*)(ws + 1220608);           // 6144 B
  float* bnsh = (float*)(ws + 1226752);           // 6144 B
  float* attp = (float*)(ws + 1232896);           // G*20*4 B
  size_t poolOff = (1232896 + (size_t)G*80 + 255) & ~(size_t)255;
  f16* pooled = (f16*)(ws + poolOff);             // G*1536*2 B

  prep_kernel<<<256, 256, 0, stream>>>(
      W[0],W[1],W[2],W[3],W[4],W[5],W[6],W[7],W[8],
      fcW, bn_g, bn_b, bn_rm, bn_rv, att,
      wt, fcWh, bnsc, bnsh, attp, G);

  const int gb = (G + 3) / 4;
  gcn_kernel<<<gb, 256, 0, stream>>>(
      x, wt, attp,
      B[0],B[1],B[2],B[3],B[4],B[5],B[6],B[7],B[8],
      pooled, G);

  head_kernel<<<(G + 15)/16, 256, 0, stream>>>(
      pooled, fcWh, fcB, bnsc, bnsh, out, G);
}